// Round 1
// baseline (130.663 us; speedup 1.0000x reference)
//
#include <hip/hip_runtime.h>

#define D_ 64
#define S_ 2048
#define B_ 16
#define QT 64
#define KVT 128

typedef short short8 __attribute__((ext_vector_type(8)));
typedef short short4a __attribute__((ext_vector_type(4)));
typedef float floatx4 __attribute__((ext_vector_type(4)));
typedef unsigned uint2v __attribute__((ext_vector_type(2)));

// exp(s/sqrt(2048)) == exp2(s * SC2); SC2 is pre-folded into the K pack.
#define SC2 (1.4426950408889634f / 45.254833995939045f)

__device__ __forceinline__ unsigned short f2bf(float f) {
  unsigned u = __builtin_bit_cast(unsigned, f);
  u += 0x7fffu + ((u >> 16) & 1u);   // round-to-nearest-even
  return (unsigned short)(u >> 16);
}

// 16x16x16 bf16 MFMA: B-operand k-mapping (k=4g+j) == C-layout m-mapping (m=4g+r),
// so a packed C-fragment feeds directly as B. A: m=ln, k=4g+j.
__device__ __forceinline__ floatx4 mfma16(short4a a, short4a b, floatx4 c) {
#if __has_builtin(__builtin_amdgcn_mfma_f32_16x16x16bf16_1k)
  return __builtin_amdgcn_mfma_f32_16x16x16bf16_1k(a, b, c, 0, 0, 0);
#else
  floatx4 d;
  asm volatile("v_mfma_f32_16x16x16_bf16 %0, %1, %2, %3"
               : "=v"(d) : "v"(a), "v"(b), "v"(c));
  return d;
#endif
}

// ---------------------------------------------------------------------------
// pack_all: bid<128 -> Q [D][S][B]f32 -> [B][S][D]bf16
//           bid<256 -> K  same, pre-scaled by SC2
//           else    -> V -> [B][D][S]bf16 (transposed)
// ---------------------------------------------------------------------------
__global__ __launch_bounds__(256) void pack_all(const float* __restrict__ Q,
                                                const float* __restrict__ K,
                                                const float* __restrict__ V,
                                                unsigned short* __restrict__ Qp,
                                                unsigned short* __restrict__ Kp,
                                                unsigned short* __restrict__ Vt) {
  __shared__ __align__(16) unsigned short tile[256][72];
  const int t = threadIdx.x;
  const int bid = blockIdx.x;
  if (bid < 256) {
    const bool isK = bid >= 128;
    const float* src = isK ? K : Q;
    unsigned short* dst = isK ? Kp : Qp;
    const float scale = isK ? SC2 : 1.0f;
    const int s0 = (bid & 127) * 16;
#pragma unroll
    for (int i = 0; i < 16; i++) {
      int j = i * 256 + t;
      int d = j >> 6;
      int sb4 = (j & 63) * 4;
      const float4 v = *(const float4*)(src + (size_t)d * (S_ * B_) + s0 * B_ + sb4);
      float vv[4] = {v.x, v.y, v.z, v.w};
#pragma unroll
      for (int k = 0; k < 4; k++) {
        int sb = sb4 + k;                    // si = sb>>4, b = sb&15
        tile[(sb & 15) * 16 + (sb >> 4)][d] = f2bf(vv[k] * scale);
      }
    }
    __syncthreads();
#pragma unroll
    for (int i = 0; i < 8; i++) {
      int j = i * 256 + t;
      int r = j >> 3, c = j & 7;
      int b = r >> 4, si = r & 15;
      uint4 v = *(const uint4*)(&tile[r][c * 8]);
      *(uint4*)(dst + ((size_t)(b * S_ + s0 + si) * D_ + c * 8)) = v;
    }
  } else {
    const int vb = bid - 256;
    const int s0 = (vb & 31) * 64;
    const int d0 = (vb >> 5) * 16;
#pragma unroll
    for (int i = 0; i < 16; i++) {
      int j = i * 256 + t;
      int dd = j >> 8;
      int sb4 = (j & 255) * 4;
      const float4 v = *(const float4*)(V + (size_t)(d0 + dd) * (S_ * B_) + s0 * B_ + sb4);
      float vv[4] = {v.x, v.y, v.z, v.w};
#pragma unroll
      for (int k = 0; k < 4; k++) {
        int sb = sb4 + k;
        tile[(sb & 15) * 16 + dd][sb >> 4] = f2bf(vv[k]);
      }
    }
    __syncthreads();
#pragma unroll
    for (int i = 0; i < 8; i++) {
      int j = i * 256 + t;
      int r = j >> 3, c = j & 7;
      int b = r >> 4, dd = r & 15;
      uint4 v = *(const uint4*)(&tile[r][c * 8]);
      *(uint4*)(Vt + ((size_t)(b * D_ + d0 + dd) * S_ + s0 + c * 8)) = v;
    }
  }
}

// ---------------------------------------------------------------------------
// attn: S^T = K.Q^T (16x16x32, kf/qf direct from global);
//       P packed in-register == B-frag of 16x16x16 PV MFMA (no LDS for P);
//       O^T_w = V^T . P^T over wave-private 32-kv slices; one LDS reduction.
//       V frags read DIRECT from global (L2-resident, zero reuse per element
//       -> LDS staging was pure overhead) with 1-tile register prefetch.
//       NO barriers in the main loop: waves fully decoupled.
// ---------------------------------------------------------------------------
__global__ __launch_bounds__(256, 2) void attn(const unsigned short* __restrict__ Qp,
                                               const unsigned short* __restrict__ Kp,
                                               const unsigned short* __restrict__ Vt,
                                               float* __restrict__ Ot) {
  // red: [4 waves][64 q][68 d] f32 = 69632 B; lred 1 KB. (V no longer staged.)
  __shared__ __align__(16) char smem_[69632 + 1024];
  float* red = (float*)smem_;
  float* lred = (float*)(smem_ + 69632);

  const int tid = threadIdx.x;
  const int w = tid >> 6, l = tid & 63, g = l >> 4, ln = l & 15;
  const int b = blockIdx.x & 15;                // XCD-pinned batch
  const int q0 = (int)(blockIdx.x >> 4) * QT;
  const int kvw = w * 32;

  const unsigned short* Qb = Qp + (size_t)b * S_ * D_;
  const unsigned short* Kb = Kp + (size_t)b * S_ * D_;
  const unsigned short* Vb = Vt + (size_t)b * D_ * S_;

  // Q^T B-frags direct from global: n=q=16nf+ln, k=d=32ks+8g+j (sector-aligned)
  short8 qf[4][2];
#pragma unroll
  for (int nf = 0; nf < 4; nf++)
#pragma unroll
    for (int ks = 0; ks < 2; ks++)
      qf[nf][ks] = *(const short8*)(Qb + (size_t)(q0 + nf * 16 + ln) * D_ + ks * 32 + g * 8);

  // K frags tile 0 (wave-private kv slice rows)
  short8 kf[2][2];
#pragma unroll
  for (int mf = 0; mf < 2; mf++)
#pragma unroll
    for (int ks = 0; ks < 2; ks++)
      kf[mf][ks] = *(const short8*)(Kb + (size_t)(kvw + mf * 16 + ln) * D_ + ks * 32 + g * 8);

  // V^T A-frags tile 0, direct from global: m=d=16mfd+ln, k=kv=4g+j (+mf*16)
  const unsigned short* Vw = Vb + (size_t)ln * S_ + kvw + g * 4;
  short4a vf[4][2];
#pragma unroll
  for (int mfd = 0; mfd < 4; mfd++)
#pragma unroll
    for (int mf = 0; mf < 2; mf++)
      vf[mfd][mf] = *(const short4a*)(Vw + (size_t)(mfd * 16) * S_ + mf * 16);

  const short4a ones = {(short)0x3F80, (short)0x3F80, (short)0x3F80, (short)0x3F80};
  floatx4 oacc[4][4];                           // [d=16mfd+4g+r][q=16nf+ln], partial over wave's kv
  floatx4 dacc[4];                              // denominator partials (all rows equal)
#pragma unroll
  for (int mfd = 0; mfd < 4; mfd++)
#pragma unroll
    for (int nf = 0; nf < 4; nf++) oacc[mfd][nf] = (floatx4){0.f, 0.f, 0.f, 0.f};
#pragma unroll
  for (int nf = 0; nf < 4; nf++) dacc[nf] = (floatx4){0.f, 0.f, 0.f, 0.f};

  for (int t = 0; t < 16; t++) {
    const int kvn = ((t + 1) * KVT) & (S_ - 1);     // next tile (wraps harmlessly)

    // ---- S^T[32 kv][64 q] = K . Q^T  (pre-scaled: sacc = s*SC2) ----
    floatx4 sacc[2][4];
#pragma unroll
    for (int mf = 0; mf < 2; mf++)
#pragma unroll
      for (int nf = 0; nf < 4; nf++) sacc[mf][nf] = (floatx4){0.f, 0.f, 0.f, 0.f};
    __builtin_amdgcn_s_setprio(1);
#pragma unroll
    for (int ks = 0; ks < 2; ks++)
#pragma unroll
      for (int mf = 0; mf < 2; mf++)
#pragma unroll
        for (int nf = 0; nf < 4; nf++)
          sacc[mf][nf] = __builtin_amdgcn_mfma_f32_16x16x32_bf16(kf[mf][ks], qf[nf][ks],
                                                                 sacc[mf][nf], 0, 0, 0);
    __builtin_amdgcn_s_setprio(0);

    // prefetch K frags for next tile
#pragma unroll
    for (int mf = 0; mf < 2; mf++)
#pragma unroll
      for (int ks = 0; ks < 2; ks++)
        kf[mf][ks] = *(const short8*)(Kb + (size_t)(kvn + kvw + mf * 16 + ln) * D_ + ks * 32 + g * 8);

    // ---- P = exp2(sacc), packed in-register: C-frag -> B-frag (16x16x16) ----
    short4a pb[2][4];
#pragma unroll
    for (int mf = 0; mf < 2; mf++)
#pragma unroll
      for (int nf = 0; nf < 4; nf++) {
        unsigned u0 = __builtin_bit_cast(unsigned, __builtin_amdgcn_exp2f(sacc[mf][nf][0])) + 0x8000u;
        unsigned u1 = __builtin_bit_cast(unsigned, __builtin_amdgcn_exp2f(sacc[mf][nf][1])) + 0x8000u;
        unsigned u2 = __builtin_bit_cast(unsigned, __builtin_amdgcn_exp2f(sacc[mf][nf][2])) + 0x8000u;
        unsigned u3 = __builtin_bit_cast(unsigned, __builtin_amdgcn_exp2f(sacc[mf][nf][3])) + 0x8000u;
        unsigned lo = __builtin_amdgcn_perm(u1, u0, 0x07060302u);  // [bf16(e0), bf16(e1)]
        unsigned hi = __builtin_amdgcn_perm(u3, u2, 0x07060302u);  // [bf16(e2), bf16(e3)]
        pb[mf][nf] = __builtin_bit_cast(short4a, (uint2v){lo, hi});
      }

    __builtin_amdgcn_s_setprio(1);
    // ---- denominator: ones-row MFMA (colsum of P) ----
#pragma unroll
    for (int mf = 0; mf < 2; mf++)
#pragma unroll
      for (int nf = 0; nf < 4; nf++)
        dacc[nf] = mfma16(ones, pb[mf][nf], dacc[nf]);

    // ---- O^T += V^T . P^T over wave's 32 kv (2 chunks of 16) ----
#pragma unroll
    for (int mfd = 0; mfd < 4; mfd++)
#pragma unroll
      for (int mf = 0; mf < 2; mf++) {
#pragma unroll
        for (int nf = 0; nf < 4; nf++)
          oacc[mfd][nf] = mfma16(vf[mfd][mf], pb[mf][nf], oacc[mfd][nf]);
      }
    __builtin_amdgcn_s_setprio(0);

    // prefetch V frags for next tile (regs free after PV issue; consumed next
    // iter after QK+exp+denom -> L2 latency fully hidden)
#pragma unroll
    for (int mfd = 0; mfd < 4; mfd++)
#pragma unroll
      for (int mf = 0; mf < 2; mf++)
        vf[mfd][mf] = *(const short4a*)(Vw + (size_t)(mfd * 16) * S_ + kvn + mf * 16);
  }

  // ---- cross-wave reduction: O = sum_w O_w, denom = sum_w dacc ----
  if (g == 0) {
#pragma unroll
    for (int nf = 0; nf < 4; nf++) lred[w * 64 + nf * 16 + ln] = dacc[nf][0];
  }
#pragma unroll
  for (int mfd = 0; mfd < 4; mfd++)
#pragma unroll
    for (int nf = 0; nf < 4; nf++)
      *(floatx4*)(&red[w * 4352 + (nf * 16 + ln) * 68 + mfd * 16 + g * 4]) = oacc[mfd][nf];
  __syncthreads();

  // wave w reduces+stores d-quarter [16w,16w+16) for all 64 q; lane l = q
  const int q = l;
  const float denom = lred[q] + lred[64 + q] + lred[128 + q] + lred[192 + q];
  const float linv = 1.0f / denom;
#pragma unroll
  for (int i = 0; i < 4; i++) {
    floatx4 s = (floatx4){0.f, 0.f, 0.f, 0.f};
#pragma unroll
    for (int w2 = 0; w2 < 4; w2++)
      s += *(const floatx4*)(&red[w2 * 4352 + q * 68 + w * 16 + i * 4]);
    s *= linv;
#pragma unroll
    for (int r = 0; r < 4; r++)
      Ot[(size_t)(b * D_ + w * 16 + i * 4 + r) * S_ + q0 + q] = s[r];
  }
}

// ---------------------------------------------------------------------------
// Unpack: Ot [B][D][S] f32 -> out [D][S][B] f32 (verified round 3).
// ---------------------------------------------------------------------------
__global__ __launch_bounds__(256) void unpack_o(const float* __restrict__ Ot,
                                                float* __restrict__ out) {
  const int d0 = (int)(blockIdx.x & 7) * 8;
  const int s0 = (int)(blockIdx.x >> 3) * 64;
  __shared__ float u[8 * 1024];
  const int t = threadIdx.x;
#pragma unroll
  for (int i = 0; i < 8; i++) {
    int j = i * 256 + t;
    int d = j >> 8, bb = (j >> 4) & 15, c = j & 15;
    float4 v = *(const float4*)(Ot + (size_t)(bb * D_ + d0 + d) * S_ + s0 + c * 4);
    float vv[4] = {v.x, v.y, v.z, v.w};
#pragma unroll
    for (int k = 0; k < 4; k++) {
      int si = c * 4 + k;
      int W = si * 16 + bb;
      int Wp = W ^ ((si & 15) << 2);
      u[d * 1024 + Wp] = vv[k];
    }
  }
  __syncthreads();
#pragma unroll
  for (int i = 0; i < 8; i++) {
    int j = i * 256 + t;
    int d = j >> 8, c2 = j & 255;
    int G = c2 ^ ((c2 >> 2) & 15);
    float4 v = *(const float4*)(&u[d * 1024 + G * 4]);
    *(float4*)(out + (size_t)(d0 + d) * (S_ * B_) + s0 * B_ + c2 * 4) = v;
  }
}

// ---------------------------------------------------------------------------
extern "C" void kernel_launch(void* const* d_in, const int* in_sizes, int n_in,
                              void* d_out, int out_size, void* d_ws, size_t ws_size,
                              hipStream_t stream) {
  const float* Q = (const float*)d_in[0];    // f32 [D][S][B]
  const float* K = (const float*)d_in[1];
  const float* V = (const float*)d_in[2];
  float* out = (float*)d_out;                // f32 [D][S][B]
  char* ws = (char*)d_ws;
  unsigned short* Qp = (unsigned short*)(ws);                  // 4 MB bf16 [B][S][D]
  unsigned short* Kp = (unsigned short*)(ws + (4u << 20));     // 4 MB bf16 [B][S][D], pre-scaled
  unsigned short* Vt = (unsigned short*)(ws + (8u << 20));     // 4 MB bf16 [B][D][S]
  float* Ot = (float*)(ws + (12u << 20));                      // 8 MB f32  [B][D][S]

  hipLaunchKernelGGL(pack_all, dim3(384), dim3(256), 0, stream, Q, K, V, Qp, Kp, Vt);
  hipLaunchKernelGGL(attn, dim3(512), dim3(256), 0, stream, Qp, Kp, Vt, Ot);
  hipLaunchKernelGGL(unpack_o, dim3(256), dim3(256), 0, stream, Ot, out);
}

// Round 2
// 104.313 us; speedup vs baseline: 1.2526x; 1.2526x over previous
//
#include <hip/hip_runtime.h>

#define D_ 64
#define S_ 2048
#define B_ 16
#define QT 64
#define KVT 128

typedef short short8 __attribute__((ext_vector_type(8)));
typedef short short4a __attribute__((ext_vector_type(4)));
typedef float floatx4 __attribute__((ext_vector_type(4)));
typedef unsigned uint2v __attribute__((ext_vector_type(2)));

// exp(s/sqrt(2048)) == exp2(s * SC2); SC2 is pre-folded into the K pack.
#define SC2 (1.4426950408889634f / 45.254833995939045f)

__device__ __forceinline__ unsigned short f2bf(float f) {
  unsigned u = __builtin_bit_cast(unsigned, f);
  u += 0x7fffu + ((u >> 16) & 1u);   // round-to-nearest-even
  return (unsigned short)(u >> 16);
}

// 16x16x16 bf16 MFMA: B-operand k-mapping (k=4g+j) == C-layout m-mapping (m=4g+r),
// so a packed C-fragment feeds directly as B. A: m=ln, k=4g+j.
__device__ __forceinline__ floatx4 mfma16(short4a a, short4a b, floatx4 c) {
#if __has_builtin(__builtin_amdgcn_mfma_f32_16x16x16bf16_1k)
  return __builtin_amdgcn_mfma_f32_16x16x16bf16_1k(a, b, c, 0, 0, 0);
#else
  floatx4 d;
  asm volatile("v_mfma_f32_16x16x16_bf16 %0, %1, %2, %3"
               : "=v"(d) : "v"(a), "v"(b), "v"(c));
  return d;
#endif
}

// ---------------------------------------------------------------------------
// FRAGMENT-ORDERED layouts (so attn's loads are lane-contiguous):
//   Q/K: per b, 128 row-tiles (16 rows x 64 d). Element (row,d):
//        rb=row>>4, ln=row&15, ks=d>>5, g=(d>>3)&3, j=d&7
//        addr = (b*128+rb)*1024 + ks*512 + (g*16+ln)*8 + j
//        -> attn lane l=16g+ln loads short8 at tile + ks*512 + l*8.
//   V:   per b, 128 kv-tiles x 4 d-tiles (16 d x 16 kv). Element (d,kv):
//        kvblk=kv>>4, dblk=d>>4, ln=d&15, g=(kv>>2)&3, j=kv&3
//        addr = ((b*128+kvblk)*4+dblk)*256 + (g*16+ln)*4 + j
//        -> attn lane l loads short4a at tile + l*4.
// ---------------------------------------------------------------------------
__global__ __launch_bounds__(256) void pack_all(const float* __restrict__ Q,
                                                const float* __restrict__ K,
                                                const float* __restrict__ V,
                                                unsigned short* __restrict__ Qp,
                                                unsigned short* __restrict__ Kp,
                                                unsigned short* __restrict__ Vt) {
  __shared__ __align__(16) unsigned short tile[256][72];
  const int t = threadIdx.x;
  const int bid = blockIdx.x;
  if (bid < 256) {
    const bool isK = bid >= 128;
    const float* src = isK ? K : Q;
    unsigned short* dst = isK ? Kp : Qp;
    const float scale = isK ? SC2 : 1.0f;
    const int rb = bid & 127;
    const int s0 = rb * 16;
#pragma unroll
    for (int i = 0; i < 16; i++) {
      int j = i * 256 + t;
      int d = j >> 6;
      int sb4 = (j & 63) * 4;
      const float4 v = *(const float4*)(src + (size_t)d * (S_ * B_) + s0 * B_ + sb4);
      float vv[4] = {v.x, v.y, v.z, v.w};
#pragma unroll
      for (int k = 0; k < 4; k++) {
        int sb = sb4 + k;                    // si = sb>>4, b = sb&15
        tile[(sb & 15) * 16 + (sb >> 4)][d] = f2bf(vv[k] * scale);
      }
    }
    __syncthreads();
#pragma unroll
    for (int i = 0; i < 8; i++) {
      int j = i * 256 + t;
      int r = j >> 3, c = j & 7;
      int b = r >> 4, si = r & 15;
      uint4 v = *(const uint4*)(&tile[r][c * 8]);
      // frag order: ks=c>>2, g=c&3, ln=si, j=0..7 contiguous -> one uint4
      *(uint4*)(dst + (((size_t)(b * 128 + rb)) << 10) + ((c >> 2) << 9) +
                (((c & 3) * 16 + si) << 3)) = v;
    }
  } else {
    const int vb = bid - 256;
    const int s0 = (vb & 31) * 64;
    const int d0 = (vb >> 5) * 16;
    const int dblk = vb >> 5;
#pragma unroll
    for (int i = 0; i < 16; i++) {
      int j = i * 256 + t;
      int dd = j >> 8;
      int sb4 = (j & 255) * 4;
      const float4 v = *(const float4*)(V + (size_t)(d0 + dd) * (S_ * B_) + s0 * B_ + sb4);
      float vv[4] = {v.x, v.y, v.z, v.w};
#pragma unroll
      for (int k = 0; k < 4; k++) {
        int sb = sb4 + k;
        tile[(sb & 15) * 16 + dd][sb >> 4] = f2bf(vv[k]);
      }
    }
    __syncthreads();
#pragma unroll
    for (int i = 0; i < 8; i++) {
      int j = i * 256 + t;
      int r = j >> 3, c = j & 7;
      int b = r >> 4, dd = r & 15;
      uint4 v = *(const uint4*)(&tile[r][c * 8]);
      // kv = s0 + c*8 + e: kvblk = (vb&31)*4 + (c>>1), g0 = (c&1)*2
      int kvblk = (vb & 31) * 4 + (c >> 1);
      int g0 = (c & 1) * 2;
      size_t a0 = (((size_t)(b * 128 + kvblk) * 4 + dblk) << 8) + ((g0 * 16 + dd) << 2);
      *(uint2*)(Vt + a0) = make_uint2(v.x, v.y);          // g0,   j=0..3
      *(uint2*)(Vt + a0 + 64) = make_uint2(v.z, v.w);     // g0+1, j=0..3
    }
  }
}

// ---------------------------------------------------------------------------
// attn: S^T = K.Q^T (16x16x32, kf/qf direct from global, frag-ordered ->
//       every load is lane-contiguous); P packed in-register == B-frag of
//       16x16x16 PV MFMA; O^T_w = V^T . P^T over wave-private 32-kv slices;
//       one LDS reduction. NO barriers in the main loop.
// ---------------------------------------------------------------------------
__global__ __launch_bounds__(256, 2) void attn(const unsigned short* __restrict__ Qp,
                                               const unsigned short* __restrict__ Kp,
                                               const unsigned short* __restrict__ Vt,
                                               float* __restrict__ Ot) {
  // red: [4 waves][64 q][68 d] f32 = 69632 B; lred 1 KB.
  __shared__ __align__(16) char smem_[69632 + 1024];
  float* red = (float*)smem_;
  float* lred = (float*)(smem_ + 69632);

  const int tid = threadIdx.x;
  const int w = tid >> 6, l = tid & 63, g = l >> 4, ln = l & 15;
  const int b = blockIdx.x & 15;                // XCD-pinned batch
  const int q0 = (int)(blockIdx.x >> 4) * QT;

  const unsigned short* Qb = Qp + ((size_t)b << 17);   // b * 131072
  const unsigned short* Kb = Kp + ((size_t)b << 17);
  const unsigned short* Vb = Vt + ((size_t)b << 17);

  // per-wave/lane base pointers into the fragment-ordered buffers
  const unsigned short* Qw = Qb + (((size_t)(q0 >> 4)) << 10) + l * 8;
  const unsigned short* Kw = Kb + w * 2048 + l * 8;    // wave's 2 row-tiles/128-kv
  const unsigned short* Vw = Vb + w * 2048 + l * 4;    // wave's 2 kv-tiles x 4 dblk

  // Q^T B-frags (once per block): n=q=16nf+ln, k=d=32ks+8g+j
  short8 qf[4][2];
#pragma unroll
  for (int nf = 0; nf < 4; nf++)
#pragma unroll
    for (int ks = 0; ks < 2; ks++)
      qf[nf][ks] = *(const short8*)(Qw + nf * 1024 + ks * 512);

  // K frags tile 0 (wave-private kv slice rows)
  short8 kf[2][2];
#pragma unroll
  for (int mf = 0; mf < 2; mf++)
#pragma unroll
    for (int ks = 0; ks < 2; ks++)
      kf[mf][ks] = *(const short8*)(Kw + mf * 1024 + ks * 512);

  // V^T A-frags tile 0: m=d=16mfd+ln, k=kv=4g+j (+mf*16)
  short4a vf[4][2];
#pragma unroll
  for (int mfd = 0; mfd < 4; mfd++)
#pragma unroll
    for (int mf = 0; mf < 2; mf++)
      vf[mfd][mf] = *(const short4a*)(Vw + mf * 1024 + mfd * 256);

  const short4a ones = {(short)0x3F80, (short)0x3F80, (short)0x3F80, (short)0x3F80};
  floatx4 oacc[4][4];                           // [d=16mfd+4g+r][q=16nf+ln]
  floatx4 dacc[4];                              // denominator partials
#pragma unroll
  for (int mfd = 0; mfd < 4; mfd++)
#pragma unroll
    for (int nf = 0; nf < 4; nf++) oacc[mfd][nf] = (floatx4){0.f, 0.f, 0.f, 0.f};
#pragma unroll
  for (int nf = 0; nf < 4; nf++) dacc[nf] = (floatx4){0.f, 0.f, 0.f, 0.f};

  for (int t = 0; t < 16; t++) {
    const int tn = (((t + 1) & 15)) * 8192;     // next tile's frag offset (wraps)

    // ---- S^T[32 kv][64 q] = K . Q^T  (pre-scaled: sacc = s*SC2) ----
    floatx4 sacc[2][4];
#pragma unroll
    for (int mf = 0; mf < 2; mf++)
#pragma unroll
      for (int nf = 0; nf < 4; nf++) sacc[mf][nf] = (floatx4){0.f, 0.f, 0.f, 0.f};
    __builtin_amdgcn_s_setprio(1);
#pragma unroll
    for (int ks = 0; ks < 2; ks++)
#pragma unroll
      for (int mf = 0; mf < 2; mf++)
#pragma unroll
        for (int nf = 0; nf < 4; nf++)
          sacc[mf][nf] = __builtin_amdgcn_mfma_f32_16x16x32_bf16(kf[mf][ks], qf[nf][ks],
                                                                 sacc[mf][nf], 0, 0, 0);
    __builtin_amdgcn_s_setprio(0);

    // prefetch K frags for next tile (coalesced: 64 lanes x 16 B contiguous)
#pragma unroll
    for (int mf = 0; mf < 2; mf++)
#pragma unroll
      for (int ks = 0; ks < 2; ks++)
        kf[mf][ks] = *(const short8*)(Kw + tn + mf * 1024 + ks * 512);

    // ---- P = exp2(sacc), packed in-register: C-frag -> B-frag (16x16x16) ----
    short4a pb[2][4];
#pragma unroll
    for (int mf = 0; mf < 2; mf++)
#pragma unroll
      for (int nf = 0; nf < 4; nf++) {
        unsigned u0 = __builtin_bit_cast(unsigned, __builtin_amdgcn_exp2f(sacc[mf][nf][0])) + 0x8000u;
        unsigned u1 = __builtin_bit_cast(unsigned, __builtin_amdgcn_exp2f(sacc[mf][nf][1])) + 0x8000u;
        unsigned u2 = __builtin_bit_cast(unsigned, __builtin_amdgcn_exp2f(sacc[mf][nf][2])) + 0x8000u;
        unsigned u3 = __builtin_bit_cast(unsigned, __builtin_amdgcn_exp2f(sacc[mf][nf][3])) + 0x8000u;
        unsigned lo = __builtin_amdgcn_perm(u1, u0, 0x07060302u);  // [bf16(e0), bf16(e1)]
        unsigned hi = __builtin_amdgcn_perm(u3, u2, 0x07060302u);  // [bf16(e2), bf16(e3)]
        pb[mf][nf] = __builtin_bit_cast(short4a, (uint2v){lo, hi});
      }

    __builtin_amdgcn_s_setprio(1);
    // ---- denominator: ones-row MFMA (colsum of P) ----
#pragma unroll
    for (int mf = 0; mf < 2; mf++)
#pragma unroll
      for (int nf = 0; nf < 4; nf++)
        dacc[nf] = mfma16(ones, pb[mf][nf], dacc[nf]);

    // ---- O^T += V^T . P^T over wave's 32 kv (2 chunks of 16) ----
#pragma unroll
    for (int mfd = 0; mfd < 4; mfd++)
#pragma unroll
      for (int mf = 0; mf < 2; mf++) {
#pragma unroll
        for (int nf = 0; nf < 4; nf++)
          oacc[mfd][nf] = mfma16(vf[mfd][mf], pb[mf][nf], oacc[mfd][nf]);
      }
    __builtin_amdgcn_s_setprio(0);

    // prefetch V frags for next tile (coalesced: 64 lanes x 8 B contiguous)
#pragma unroll
    for (int mfd = 0; mfd < 4; mfd++)
#pragma unroll
      for (int mf = 0; mf < 2; mf++)
        vf[mfd][mf] = *(const short4a*)(Vw + tn + mf * 1024 + mfd * 256);
  }

  // ---- cross-wave reduction: O = sum_w O_w, denom = sum_w dacc ----
  if (g == 0) {
#pragma unroll
    for (int nf = 0; nf < 4; nf++) lred[w * 64 + nf * 16 + ln] = dacc[nf][0];
  }
#pragma unroll
  for (int mfd = 0; mfd < 4; mfd++)
#pragma unroll
    for (int nf = 0; nf < 4; nf++)
      *(floatx4*)(&red[w * 4352 + (nf * 16 + ln) * 68 + mfd * 16 + g * 4]) = oacc[mfd][nf];
  __syncthreads();

  // wave w reduces+stores d-quarter [16w,16w+16) for all 64 q; lane l = q
  const int q = l;
  const float denom = lred[q] + lred[64 + q] + lred[128 + q] + lred[192 + q];
  const float linv = 1.0f / denom;
#pragma unroll
  for (int i = 0; i < 4; i++) {
    floatx4 s = (floatx4){0.f, 0.f, 0.f, 0.f};
#pragma unroll
    for (int w2 = 0; w2 < 4; w2++)
      s += *(const floatx4*)(&red[w2 * 4352 + q * 68 + w * 16 + i * 4]);
    s *= linv;
#pragma unroll
    for (int r = 0; r < 4; r++)
      Ot[(size_t)(b * D_ + w * 16 + i * 4 + r) * S_ + q0 + q] = s[r];
  }
}

// ---------------------------------------------------------------------------
// Unpack: Ot [B][D][S] f32 -> out [D][S][B] f32 (verified round 3).
// ---------------------------------------------------------------------------
__global__ __launch_bounds__(256) void unpack_o(const float* __restrict__ Ot,
                                                float* __restrict__ out) {
  const int d0 = (int)(blockIdx.x & 7) * 8;
  const int s0 = (int)(blockIdx.x >> 3) * 64;
  __shared__ float u[8 * 1024];
  const int t = threadIdx.x;
#pragma unroll
  for (int i = 0; i < 8; i++) {
    int j = i * 256 + t;
    int d = j >> 8, bb = (j >> 4) & 15, c = j & 15;
    float4 v = *(const float4*)(Ot + (size_t)(bb * D_ + d0 + d) * S_ + s0 + c * 4);
    float vv[4] = {v.x, v.y, v.z, v.w};
#pragma unroll
    for (int k = 0; k < 4; k++) {
      int si = c * 4 + k;
      int W = si * 16 + bb;
      int Wp = W ^ ((si & 15) << 2);
      u[d * 1024 + Wp] = vv[k];
    }
  }
  __syncthreads();
#pragma unroll
  for (int i = 0; i < 8; i++) {
    int j = i * 256 + t;
    int d = j >> 8, c2 = j & 255;
    int G = c2 ^ ((c2 >> 2) & 15);
    float4 v = *(const float4*)(&u[d * 1024 + G * 4]);
    *(float4*)(out + (size_t)(d0 + d) * (S_ * B_) + s0 * B_ + c2 * 4) = v;
  }
}

// ---------------------------------------------------------------------------
extern "C" void kernel_launch(void* const* d_in, const int* in_sizes, int n_in,
                              void* d_out, int out_size, void* d_ws, size_t ws_size,
                              hipStream_t stream) {
  const float* Q = (const float*)d_in[0];    // f32 [D][S][B]
  const float* K = (const float*)d_in[1];
  const float* V = (const float*)d_in[2];
  float* out = (float*)d_out;                // f32 [D][S][B]
  char* ws = (char*)d_ws;
  unsigned short* Qp = (unsigned short*)(ws);                  // 4 MB bf16, frag-ordered
  unsigned short* Kp = (unsigned short*)(ws + (4u << 20));     // 4 MB bf16, frag-ordered, pre-scaled
  unsigned short* Vt = (unsigned short*)(ws + (8u << 20));     // 4 MB bf16, frag-ordered V^T
  float* Ot = (float*)(ws + (12u << 20));                      // 8 MB f32  [B][D][S]

  hipLaunchKernelGGL(pack_all, dim3(384), dim3(256), 0, stream, Q, K, V, Qp, Kp, Vt);
  hipLaunchKernelGGL(attn, dim3(512), dim3(256), 0, stream, Qp, Kp, Vt, Ot);
  hipLaunchKernelGGL(unpack_o, dim3(256), dim3(256), 0, stream, Ot, out);
}